// Round 4
// baseline (442.928 us; speedup 1.0000x reference)
//
#include <hip/hip_runtime.h>
#include <hip/hip_bf16.h>
#include <stdint.h>

#define S_LEN 4096
#define D_MODEL 1024
#define N_HEADS 16
#define D_HEAD 64
#define SCALE_LOG2E 0.1803368787f   // (1/sqrt(64)) * log2(e)

typedef __attribute__((ext_vector_type(4))) float f32x4;
typedef __attribute__((ext_vector_type(8))) __bf16 bf16x8;

__device__ __forceinline__ unsigned short f2bf(float f) {
    union { float f; unsigned u; } x{f};
    unsigned r = x.u + 0x7fff + ((x.u >> 16) & 1);
    return (unsigned short)(r >> 16);
}

__device__ __forceinline__ void gld_lds16(const void* g, void* l) {
    __builtin_amdgcn_global_load_lds(
        (const __attribute__((address_space(1))) unsigned int*)g,
        (__attribute__((address_space(3))) unsigned int*)l, 16, 0, 0);
}

// ---------------- f32 -> bf16 convert ----------------
__global__ __launch_bounds__(256) void to_bf16_k(const float* __restrict__ src,
                                                 unsigned short* __restrict__ dst, int n) {
    int i = (blockIdx.x * 256 + threadIdx.x) * 4;
    if (i < n) {
        float4 v = *(const float4*)&src[i];
        ushort4 o;
        o.x = f2bf(v.x); o.y = f2bf(v.y); o.z = f2bf(v.z); o.w = f2bf(v.w);
        *(ushort4*)&dst[i] = o;
    }
}

// ---------------- RoPE cos/sin tables ----------------
__global__ __launch_bounds__(256) void rope_tables_k(const int* __restrict__ pos,
                                                     float* __restrict__ ct,
                                                     float* __restrict__ st) {
    int i = blockIdx.x * 256 + threadIdx.x;   // [0, 4096*32)
    int s = i >> 5, k = i & 31;
    float invf = __builtin_exp2f(-(float)(2 * k) * (1.0f / 64.0f) * 13.287712379549449f);
    float ang = (float)pos[s] * invf;
    ct[i] = cosf(ang);
    st[i] = sinf(ang);
}

// ---------------- V transpose: Vrow [S][D_head*H slice] -> Vt [D][S] ----------------
// 64x64 bf16 tiles through LDS (pad stride 68), vectorized both sides.
__global__ __launch_bounds__(256) void vtrans_k(const unsigned short* __restrict__ src,
                                                unsigned short* __restrict__ dst) {
    __shared__ unsigned short tile[64 * 68];
    const int bs = blockIdx.x * 64;   // s tile
    const int bd = blockIdx.y * 64;   // d tile
    const int t = threadIdx.x;
    {
        int col = (t & 7) * 8;
        #pragma unroll
        for (int rr = 0; rr < 2; ++rr) {
            int row = rr * 32 + (t >> 3);
            const unsigned short* g = src + (size_t)(bs + row) * D_MODEL + bd + col;
            ushort4 a = *(const ushort4*)g;
            ushort4 b = *(const ushort4*)(g + 4);
            *(ushort4*)&tile[row * 68 + col] = a;
            *(ushort4*)&tile[row * 68 + col + 4] = b;
        }
    }
    __syncthreads();
    {
        int dl = t >> 2;             // 0..63 d row
        int sc = (t & 3) * 16;       // s chunk
        ushort4 o[4];
        #pragma unroll
        for (int e = 0; e < 16; ++e)
            ((unsigned short*)o)[e] = tile[(sc + e) * 68 + dl];
        unsigned short* g = dst + (size_t)(bd + dl) * S_LEN + bs + sc;
        *(ushort4*)(g + 0)  = o[0];
        *(ushort4*)(g + 4)  = o[1];
        *(ushort4*)(g + 8)  = o[2];
        *(ushort4*)(g + 12) = o[3];
    }
}

// ---------------- NT GEMM: C[m,n] = sum_k A[m,k]*B[n,k] ----------------
// MODE 1: fused QKV epilogue (RoPE on cols<2048; Q pre-scaled; V row-major dense)
// MODE 2: f32 out (row-major)
template <int MODE>
__global__ __launch_bounds__(256) void gemm_nt_k(const unsigned short* __restrict__ A,
                                                 const unsigned short* __restrict__ B,
                                                 void* __restrict__ C0,
                                                 void* __restrict__ C1,
                                                 void* __restrict__ C2,
                                                 int M, int N, int K,
                                                 const float* __restrict__ costab,
                                                 const float* __restrict__ sintab) {
    __shared__ unsigned short lA[128 * 64];
    __shared__ unsigned short lB[128 * 64];
    const int t = threadIdx.x, w = t >> 6, l = t & 63;
    const int tm = blockIdx.y * 128, tn = blockIdx.x * 128;
    const int wm = (w >> 1) * 64, wn = (w & 1) * 64;
    const int g = l >> 4, ln = l & 15;

    f32x4 acc[4][4] = {};

    for (int k0 = 0; k0 < K; k0 += 64) {
        for (int r = 0; r < 4; ++r) {
            int row = 8 * (4 * r + w) + (l >> 3);
            const unsigned short* ga = A + (size_t)(tm + row) * K + k0 + (l & 7) * 8;
            gld_lds16(ga, &lA[(4 * r + w) * 512]);
            const unsigned short* gb = B + (size_t)(tn + row) * K + k0 + (l & 7) * 8;
            gld_lds16(gb, &lB[(4 * r + w) * 512]);
        }
        asm volatile("s_waitcnt vmcnt(0)" ::: "memory");
        __syncthreads();

        for (int kk = 0; kk < 2; ++kk) {
            bf16x8 af[4], bf[4];
            for (int i = 0; i < 4; ++i) {
                af[i] = *(const bf16x8*)&lA[(wm + i * 16 + ln) * 64 + kk * 32 + g * 8];
                bf[i] = *(const bf16x8*)&lB[(wn + i * 16 + ln) * 64 + kk * 32 + g * 8];
            }
            for (int i = 0; i < 4; ++i)
                for (int j = 0; j < 4; ++j)
                    acc[i][j] = __builtin_amdgcn_mfma_f32_16x16x32_bf16(af[i], bf[j], acc[i][j], 0, 0, 0);
        }
        __syncthreads();
    }

    // epilogue
    for (int i = 0; i < 4; ++i) {
        for (int j = 0; j < 4; ++j) {
            int col = tn + wn + j * 16 + ln;
            for (int r = 0; r < 4; ++r) {
                int row = tm + wm + i * 16 + g * 4 + r;
                float v = acc[i][j][r];
                if (MODE == 1) {
                    if (col < 2048) {
                        float p = __shfl_xor(v, 1, 64);
                        int dd = col & 63;
                        int kidx = dd >> 1;
                        float c = costab[row * 32 + kidx];
                        float s = sintab[row * 32 + kidx];
                        v = (dd & 1) ? (s * p + c * v) : (c * v - s * p);
                        if (col < 1024)
                            ((unsigned short*)C0)[(size_t)row * 1024 + col] = f2bf(v * SCALE_LOG2E);
                        else
                            ((unsigned short*)C1)[(size_t)row * 1024 + (col - 1024)] = f2bf(v);
                    } else {
                        // V: row-major dense (coalesced); transposed later by vtrans_k
                        ((unsigned short*)C2)[(size_t)row * 1024 + (col - 2048)] = f2bf(v);
                    }
                } else {
                    ((float*)C0)[(size_t)row * N + col] = v;
                }
            }
        }
    }
}

// ---------------- causal flash attention (swapped QK^T and PV) ----------------
// grid: (16 heads, 64 qblocks). block: 256 thr = 4 waves, wave = 16 q rows.
__device__ __forceinline__ void stage_tiles(const unsigned short* __restrict__ Kb,
                                            const unsigned short* __restrict__ Vt,
                                            unsigned short* lK, unsigned short* lV,
                                            int h, int kt, int w, int l) {
    for (int r2 = 0; r2 < 2; ++r2) {
        int row = r2 * 32 + w * 8 + (l >> 3);
        int chunk = (l & 7) ^ (l >> 3);   // source pre-swizzle (row&7 == l>>3)
        gld_lds16(Kb + (size_t)(kt * 64 + row) * D_MODEL + h * 64 + chunk * 8,
                  lK + r2 * 2048 + w * 512);
        gld_lds16(Vt + (size_t)(h * 64 + row) * S_LEN + kt * 64 + chunk * 8,
                  lV + r2 * 2048 + w * 512);
    }
}

__global__ __launch_bounds__(256) void attn_k(const unsigned short* __restrict__ Qb,
                                              const unsigned short* __restrict__ Kb,
                                              const unsigned short* __restrict__ Vt,
                                              unsigned short* __restrict__ ctxb) {
    __shared__ unsigned short lK[2][64 * 64];   // K tile [k][d], swizzled
    __shared__ unsigned short lV[2][64 * 64];   // V^T tile [d][k], swizzled
    __shared__ unsigned short lP[4][16 * 64];   // per-wave P [q][k], swizzled

    const int t = threadIdx.x, w = t >> 6, l = t & 63;
    const int h = blockIdx.x;
    const int qb = (gridDim.y - 1) - blockIdx.y;   // heavy blocks first
    const int q0 = qb * 64 + w * 16;
    const int g = l >> 4, ln = l & 15;

    // Q fragments (B-operand for swapped QK^T; pre-scaled by scale*log2e)
    bf16x8 aq[2];
    #pragma unroll
    for (int kk = 0; kk < 2; ++kk)
        aq[kk] = *(const bf16x8*)&Qb[(size_t)(q0 + ln) * D_MODEL + h * 64 + kk * 32 + g * 8];

    f32x4 acc[4] = {};
    float rm = -INFINITY, rs = 0.0f;

    stage_tiles(Kb, Vt, &lK[0][0], &lV[0][0], h, 0, w, l);
    asm volatile("s_waitcnt vmcnt(0)" ::: "memory");
    __syncthreads();

    int cur = 0;
    for (int kt = 0; kt <= qb; ++kt) {
        if (kt < qb)
            stage_tiles(Kb, Vt, &lK[cur ^ 1][0], &lV[cur ^ 1][0], h, kt + 1, w, l);

        // ---- S^T = K Q^T  (lane: q = ln; k = ct*16 + g*4 + r) ----
        float p[16];
        #pragma unroll
        for (int ct = 0; ct < 4; ++ct) {
            f32x4 z = {};
            #pragma unroll
            for (int kk = 0; kk < 2; ++kk) {
                int row = ct * 16 + ln;
                int off = (row * 128 + kk * 64 + g * 16) ^ ((row & 7) << 4);
                bf16x8 ak = *(const bf16x8*)((const char*)&lK[cur][0] + off);
                z = __builtin_amdgcn_mfma_f32_16x16x32_bf16(ak, aq[kk], z, 0, 0, 0);
            }
            #pragma unroll
            for (int r = 0; r < 4; ++r) p[ct * 4 + r] = z[r];
        }

        // ---- causal mask (diagonal tile only) ----
        if (kt == qb) {
            int qg = q0 + ln;
            #pragma unroll
            for (int ct = 0; ct < 4; ++ct)
                #pragma unroll
                for (int r = 0; r < 4; ++r)
                    if (kt * 64 + ct * 16 + g * 4 + r > qg) p[ct * 4 + r] = -INFINITY;
        }

        // ---- online softmax (exp2 domain, per-lane q-row) ----
        float tmax = p[0];
        #pragma unroll
        for (int i = 1; i < 16; ++i) tmax = fmaxf(tmax, p[i]);
        tmax = fmaxf(tmax, __shfl_xor(tmax, 16, 64));
        tmax = fmaxf(tmax, __shfl_xor(tmax, 32, 64));
        float mn = fmaxf(rm, tmax);
        float fac = __builtin_amdgcn_exp2f(rm - mn);
        rm = mn;
        float ps = 0.0f;
        #pragma unroll
        for (int i = 0; i < 16; ++i) {
            float e = __builtin_amdgcn_exp2f(p[i] - rm);
            p[i] = e;
            ps += e;
        }
        ps += __shfl_xor(ps, 16, 64);
        ps += __shfl_xor(ps, 32, 64);
        rs = rs * fac + ps;
        #pragma unroll
        for (int mb = 0; mb < 4; ++mb) {
            f32x4 a = acc[mb];
            #pragma unroll
            for (int r = 0; r < 4; ++r) a[r] *= fac;
            acc[mb] = a;
        }

        // ---- pack P (bf16) to per-wave LDS, vectorized ----
        char* lpw = (char*)&lP[w][0];
        #pragma unroll
        for (int ct = 0; ct < 4; ++ct) {
            unsigned lo = (unsigned)f2bf(p[ct * 4 + 0]) | ((unsigned)f2bf(p[ct * 4 + 1]) << 16);
            unsigned hi = (unsigned)f2bf(p[ct * 4 + 2]) | ((unsigned)f2bf(p[ct * 4 + 3]) << 16);
            int off = (ln * 128 + ct * 32 + g * 8) ^ ((ln & 7) << 4);
            uint2 u; u.x = lo; u.y = hi;
            *(uint2*)(lpw + off) = u;
        }
        __syncthreads();   // full barrier between P write and PV read (replay-safe)

        // ---- ctx^T += V^T P^T  (lane: q = ln; d = mb*16 + g*4 + r) ----
        #pragma unroll
        for (int mb = 0; mb < 4; ++mb) {
            #pragma unroll
            for (int kc = 0; kc < 2; ++kc) {
                int vrow = mb * 16 + ln;
                int voff = (vrow * 128 + kc * 64 + g * 16) ^ ((vrow & 7) << 4);
                bf16x8 av = *(const bf16x8*)((const char*)&lV[cur][0] + voff);
                int poff = (ln * 128 + kc * 64 + g * 16) ^ ((ln & 7) << 4);
                bf16x8 bp = *(const bf16x8*)(lpw + poff);
                acc[mb] = __builtin_amdgcn_mfma_f32_16x16x32_bf16(av, bp, acc[mb], 0, 0, 0);
            }
        }

        asm volatile("s_waitcnt vmcnt(0)" ::: "memory");
        __syncthreads();
        cur ^= 1;
    }

    float inv = 1.0f / rs;
    #pragma unroll
    for (int mb = 0; mb < 4; ++mb)
        #pragma unroll
        for (int r = 0; r < 4; ++r)
            ctxb[(size_t)(q0 + ln) * D_MODEL + h * 64 + mb * 16 + g * 4 + r] =
                f2bf(acc[mb][r] * inv);
}

// ---------------- host side ----------------
extern "C" void kernel_launch(void* const* d_in, const int* in_sizes, int n_in,
                              void* d_out, int out_size, void* d_ws, size_t ws_size,
                              hipStream_t stream) {
    const float* x  = (const float*)d_in[0];
    const float* Wq = (const float*)d_in[1];
    const float* Wk = (const float*)d_in[2];
    const float* Wv = (const float*)d_in[3];
    const float* Wo = (const float*)d_in[4];
    const int* tpos = (const int*)d_in[5];
    float* out = (float*)d_out;

    char* ws = (char*)d_ws;
    unsigned short* xb    = (unsigned short*)(ws + 0);           // 8 MB
    unsigned short* Wqkvb = (unsigned short*)(ws + (8u << 20));  // 6 MB
    unsigned short* Wob   = (unsigned short*)(ws + (14u << 20)); // 2 MB
    unsigned short* Qbuf  = (unsigned short*)(ws + (16u << 20)); // 8 MB
    unsigned short* Kbuf  = (unsigned short*)(ws + (24u << 20)); // 8 MB
    unsigned short* Vtb   = (unsigned short*)(ws + (32u << 20)); // 8 MB
    unsigned short* ctxb  = (unsigned short*)(ws + (40u << 20)); // 8 MB
    unsigned short* Vrow  = ctxb;  // alias: Vrow dead before attn writes ctxb
    float* costab = (float*)(ws + (48u << 20));                  // 512 KB
    float* sintab = (float*)(ws + (48u << 20) + (512u << 10));   // 512 KB

    to_bf16_k<<<4096, 256, 0, stream>>>(x, xb, S_LEN * D_MODEL);
    to_bf16_k<<<1024, 256, 0, stream>>>(Wq, Wqkvb, D_MODEL * D_MODEL);
    to_bf16_k<<<1024, 256, 0, stream>>>(Wk, Wqkvb + 1024 * 1024, D_MODEL * D_MODEL);
    to_bf16_k<<<1024, 256, 0, stream>>>(Wv, Wqkvb + 2 * 1024 * 1024, D_MODEL * D_MODEL);
    to_bf16_k<<<1024, 256, 0, stream>>>(Wo, Wob, D_MODEL * D_MODEL);
    rope_tables_k<<<512, 256, 0, stream>>>(tpos, costab, sintab);

    // fused QKV projection: C = x * [Wq;Wk;Wv]^T, N = 3072
    gemm_nt_k<1><<<dim3(24, 32), 256, 0, stream>>>(xb, Wqkvb, Qbuf, Kbuf, Vrow,
                                                   S_LEN, 3072, D_MODEL, costab, sintab);

    // V transpose: Vrow [S][1024] -> Vt [1024][S]
    vtrans_k<<<dim3(S_LEN / 64, D_MODEL / 64), 256, 0, stream>>>(Vrow, Vtb);

    attn_k<<<dim3(N_HEADS, S_LEN / 64), 256, 0, stream>>>(Qbuf, Kbuf, Vtb, ctxb);

    gemm_nt_k<2><<<dim3(8, 32), 256, 0, stream>>>(ctxb, Wob, out, nullptr, nullptr,
                                                  S_LEN, D_MODEL, D_MODEL, nullptr, nullptr);
}

// Round 5
// 215.477 us; speedup vs baseline: 2.0556x; 2.0556x over previous
//
#include <hip/hip_runtime.h>
#include <hip/hip_bf16.h>
#include <stdint.h>

#define S_LEN 4096
#define D_MODEL 1024
#define N_HEADS 16
#define D_HEAD 64
#define SCALE_LOG2E 0.1803368787f   // (1/sqrt(64)) * log2(e)

typedef __attribute__((ext_vector_type(4))) float f32x4;
typedef __attribute__((ext_vector_type(8))) __bf16 bf16x8;

__device__ __forceinline__ unsigned short f2bf(float f) {
    union { float f; unsigned u; } x{f};
    unsigned r = x.u + 0x7fff + ((x.u >> 16) & 1);
    return (unsigned short)(r >> 16);
}

__device__ __forceinline__ void gld_lds16(const void* g, void* l) {
    __builtin_amdgcn_global_load_lds(
        (const __attribute__((address_space(1))) unsigned int*)g,
        (__attribute__((address_space(3))) unsigned int*)l, 16, 0, 0);
}

// ---------------- f32 -> bf16 convert ----------------
__global__ __launch_bounds__(256) void to_bf16_k(const float* __restrict__ src,
                                                 unsigned short* __restrict__ dst, int n) {
    int i = (blockIdx.x * 256 + threadIdx.x) * 4;
    if (i < n) {
        float4 v = *(const float4*)&src[i];
        ushort4 o;
        o.x = f2bf(v.x); o.y = f2bf(v.y); o.z = f2bf(v.z); o.w = f2bf(v.w);
        *(ushort4*)&dst[i] = o;
    }
}

// ---------------- RoPE cos/sin tables ----------------
__global__ __launch_bounds__(256) void rope_tables_k(const int* __restrict__ pos,
                                                     float* __restrict__ ct,
                                                     float* __restrict__ st) {
    int i = blockIdx.x * 256 + threadIdx.x;   // [0, 4096*32)
    int s = i >> 5, k = i & 31;
    float invf = __builtin_exp2f(-(float)(2 * k) * (1.0f / 64.0f) * 13.287712379549449f);
    float ang = (float)pos[s] * invf;
    ct[i] = cosf(ang);
    st[i] = sinf(ang);
}

// ---------------- V transpose: Vrow [S][1024] -> Vt [1024][S] ----------------
__global__ __launch_bounds__(256) void vtrans_k(const unsigned short* __restrict__ src,
                                                unsigned short* __restrict__ dst) {
    __shared__ unsigned short tile[64 * 68];
    const int bs = blockIdx.x * 64;   // s tile
    const int bd = blockIdx.y * 64;   // d tile
    const int t = threadIdx.x;
    {
        int col = (t & 7) * 8;
        #pragma unroll
        for (int rr = 0; rr < 2; ++rr) {
            int row = rr * 32 + (t >> 3);
            const unsigned short* g = src + (size_t)(bs + row) * D_MODEL + bd + col;
            ushort4 a = *(const ushort4*)g;
            ushort4 b = *(const ushort4*)(g + 4);
            *(ushort4*)&tile[row * 68 + col] = a;
            *(ushort4*)&tile[row * 68 + col + 4] = b;
        }
    }
    __syncthreads();
    {
        int dl = t >> 2;             // 0..63 d row
        int sc = (t & 3) * 16;       // s chunk
        ushort4 o[4];
        #pragma unroll
        for (int e = 0; e < 16; ++e)
            ((unsigned short*)o)[e] = tile[(sc + e) * 68 + dl];
        unsigned short* g = dst + (size_t)(bd + dl) * S_LEN + bs + sc;
        *(ushort4*)(g + 0)  = o[0];
        *(ushort4*)(g + 4)  = o[1];
        *(ushort4*)(g + 8)  = o[2];
        *(ushort4*)(g + 12) = o[3];
    }
}

// ---------------- NT GEMM: C[m,n] = sum_k A[m,k]*B[n,k] ----------------
// MODE 0: bf16 out; MODE 1: RoPE epilogue + scale + bf16 out; MODE 2: f32 out
// Single-output epilogue (R1-proven codegen; the R2-R4 fused 3-output variant
// triggered scratch spilling -> 1.2 GB WRITE_SIZE, 335 us).
template <int MODE>
__global__ __launch_bounds__(256) void gemm_nt_k(const unsigned short* __restrict__ A,
                                                 const unsigned short* __restrict__ B,
                                                 void* __restrict__ Cout,
                                                 int M, int N, int K,
                                                 const float* __restrict__ costab,
                                                 const float* __restrict__ sintab,
                                                 float scl) {
    __shared__ unsigned short lA[128 * 64];
    __shared__ unsigned short lB[128 * 64];
    const int t = threadIdx.x, w = t >> 6, l = t & 63;
    const int tm = blockIdx.y * 128, tn = blockIdx.x * 128;
    const int wm = (w >> 1) * 64, wn = (w & 1) * 64;
    const int g = l >> 4, ln = l & 15;

    f32x4 acc[4][4] = {};

    for (int k0 = 0; k0 < K; k0 += 64) {
        #pragma unroll
        for (int r = 0; r < 4; ++r) {
            int row = 8 * (4 * r + w) + (l >> 3);
            const unsigned short* ga = A + (size_t)(tm + row) * K + k0 + (l & 7) * 8;
            gld_lds16(ga, &lA[(4 * r + w) * 512]);
            const unsigned short* gb = B + (size_t)(tn + row) * K + k0 + (l & 7) * 8;
            gld_lds16(gb, &lB[(4 * r + w) * 512]);
        }
        asm volatile("s_waitcnt vmcnt(0)" ::: "memory");
        __syncthreads();

        #pragma unroll
        for (int kk = 0; kk < 2; ++kk) {
            bf16x8 af[4], bf[4];
            #pragma unroll
            for (int i = 0; i < 4; ++i) {
                af[i] = *(const bf16x8*)&lA[(wm + i * 16 + ln) * 64 + kk * 32 + g * 8];
                bf[i] = *(const bf16x8*)&lB[(wn + i * 16 + ln) * 64 + kk * 32 + g * 8];
            }
            #pragma unroll
            for (int i = 0; i < 4; ++i)
                #pragma unroll
                for (int j = 0; j < 4; ++j)
                    acc[i][j] = __builtin_amdgcn_mfma_f32_16x16x32_bf16(af[i], bf[j], acc[i][j], 0, 0, 0);
        }
        __syncthreads();
    }

    // epilogue
    #pragma unroll
    for (int i = 0; i < 4; ++i) {
        #pragma unroll
        for (int j = 0; j < 4; ++j) {
            int col = tn + wn + j * 16 + ln;
            #pragma unroll
            for (int r = 0; r < 4; ++r) {
                int row = tm + wm + i * 16 + g * 4 + r;
                float v = acc[i][j][r];
                if (MODE == 1) {
                    float p = __shfl_xor(v, 1, 64);
                    int dd = col & 63;
                    int kidx = dd >> 1;
                    float c = costab[row * 32 + kidx];
                    float s = sintab[row * 32 + kidx];
                    v = ((dd & 1) ? (s * p + c * v) : (c * v - s * p)) * scl;
                }
                if (MODE == 2)
                    ((float*)Cout)[(size_t)row * N + col] = v;
                else
                    ((unsigned short*)Cout)[(size_t)row * N + col] = f2bf(v);
            }
        }
    }
}

// ---------------- causal flash attention (swapped QK^T and PV) ----------------
// grid: (16 heads, 64 qblocks). block: 256 thr = 4 waves, wave = 16 q rows.
__device__ __forceinline__ void stage_tiles(const unsigned short* __restrict__ Kb,
                                            const unsigned short* __restrict__ Vt,
                                            unsigned short* lK, unsigned short* lV,
                                            int h, int kt, int w, int l) {
    for (int r2 = 0; r2 < 2; ++r2) {
        int row = r2 * 32 + w * 8 + (l >> 3);
        int chunk = (l & 7) ^ (l >> 3);   // source pre-swizzle (row&7 == l>>3)
        gld_lds16(Kb + (size_t)(kt * 64 + row) * D_MODEL + h * 64 + chunk * 8,
                  lK + r2 * 2048 + w * 512);
        gld_lds16(Vt + (size_t)(h * 64 + row) * S_LEN + kt * 64 + chunk * 8,
                  lV + r2 * 2048 + w * 512);
    }
}

__global__ __launch_bounds__(256) void attn_k(const unsigned short* __restrict__ Qb,
                                              const unsigned short* __restrict__ Kb,
                                              const unsigned short* __restrict__ Vt,
                                              unsigned short* __restrict__ ctxb) {
    __shared__ unsigned short lK[2][64 * 64];   // K tile [k][d], swizzled
    __shared__ unsigned short lV[2][64 * 64];   // V^T tile [d][k], swizzled
    __shared__ unsigned short lP[4][16 * 64];   // per-wave P [q][k], swizzled

    const int t = threadIdx.x, w = t >> 6, l = t & 63;
    const int h = blockIdx.x;
    const int qb = (gridDim.y - 1) - blockIdx.y;   // heavy blocks first
    const int q0 = qb * 64 + w * 16;
    const int g = l >> 4, ln = l & 15;

    // Q fragments (B-operand for swapped QK^T; pre-scaled by scale*log2e)
    bf16x8 aq[2];
    #pragma unroll
    for (int kk = 0; kk < 2; ++kk)
        aq[kk] = *(const bf16x8*)&Qb[(size_t)(q0 + ln) * D_MODEL + h * 64 + kk * 32 + g * 8];

    f32x4 acc[4] = {};
    float rm = -INFINITY, rs = 0.0f;

    stage_tiles(Kb, Vt, &lK[0][0], &lV[0][0], h, 0, w, l);
    asm volatile("s_waitcnt vmcnt(0)" ::: "memory");
    __syncthreads();

    int cur = 0;
    for (int kt = 0; kt <= qb; ++kt) {
        if (kt < qb)
            stage_tiles(Kb, Vt, &lK[cur ^ 1][0], &lV[cur ^ 1][0], h, kt + 1, w, l);

        // ---- S^T = K Q^T  (lane: q = ln; k = ct*16 + g*4 + r) ----
        float p[16];
        #pragma unroll
        for (int ct = 0; ct < 4; ++ct) {
            f32x4 z = {};
            #pragma unroll
            for (int kk = 0; kk < 2; ++kk) {
                int row = ct * 16 + ln;
                int off = (row * 128 + kk * 64 + g * 16) ^ ((row & 7) << 4);
                bf16x8 ak = *(const bf16x8*)((const char*)&lK[cur][0] + off);
                z = __builtin_amdgcn_mfma_f32_16x16x32_bf16(ak, aq[kk], z, 0, 0, 0);
            }
            #pragma unroll
            for (int r = 0; r < 4; ++r) p[ct * 4 + r] = z[r];
        }

        // ---- causal mask (diagonal tile only) ----
        if (kt == qb) {
            int qg = q0 + ln;
            #pragma unroll
            for (int ct = 0; ct < 4; ++ct)
                #pragma unroll
                for (int r = 0; r < 4; ++r)
                    if (kt * 64 + ct * 16 + g * 4 + r > qg) p[ct * 4 + r] = -INFINITY;
        }

        // ---- online softmax (exp2 domain, per-lane q-row) ----
        float tmax = p[0];
        #pragma unroll
        for (int i = 1; i < 16; ++i) tmax = fmaxf(tmax, p[i]);
        tmax = fmaxf(tmax, __shfl_xor(tmax, 16, 64));
        tmax = fmaxf(tmax, __shfl_xor(tmax, 32, 64));
        float mn = fmaxf(rm, tmax);
        float fac = __builtin_amdgcn_exp2f(rm - mn);
        rm = mn;
        float ps = 0.0f;
        #pragma unroll
        for (int i = 0; i < 16; ++i) {
            float e = __builtin_amdgcn_exp2f(p[i] - rm);
            p[i] = e;
            ps += e;
        }
        ps += __shfl_xor(ps, 16, 64);
        ps += __shfl_xor(ps, 32, 64);
        rs = rs * fac + ps;
        #pragma unroll
        for (int mb = 0; mb < 4; ++mb) {
            f32x4 a = acc[mb];
            #pragma unroll
            for (int r = 0; r < 4; ++r) a[r] *= fac;
            acc[mb] = a;
        }

        // ---- pack P (bf16) to per-wave LDS, vectorized ----
        char* lpw = (char*)&lP[w][0];
        #pragma unroll
        for (int ct = 0; ct < 4; ++ct) {
            unsigned lo = (unsigned)f2bf(p[ct * 4 + 0]) | ((unsigned)f2bf(p[ct * 4 + 1]) << 16);
            unsigned hi = (unsigned)f2bf(p[ct * 4 + 2]) | ((unsigned)f2bf(p[ct * 4 + 3]) << 16);
            int off = (ln * 128 + ct * 32 + g * 8) ^ ((ln & 7) << 4);
            uint2 u; u.x = lo; u.y = hi;
            *(uint2*)(lpw + off) = u;
        }
        __syncthreads();   // full barrier between P write and PV read (replay-safe)

        // ---- ctx^T += V^T P^T  (lane: q = ln; d = mb*16 + g*4 + r) ----
        #pragma unroll
        for (int mb = 0; mb < 4; ++mb) {
            #pragma unroll
            for (int kc = 0; kc < 2; ++kc) {
                int vrow = mb * 16 + ln;
                int voff = (vrow * 128 + kc * 64 + g * 16) ^ ((vrow & 7) << 4);
                bf16x8 av = *(const bf16x8*)((const char*)&lV[cur][0] + voff);
                int poff = (ln * 128 + kc * 64 + g * 16) ^ ((ln & 7) << 4);
                bf16x8 bp = *(const bf16x8*)(lpw + poff);
                acc[mb] = __builtin_amdgcn_mfma_f32_16x16x32_bf16(av, bp, acc[mb], 0, 0, 0);
            }
        }

        asm volatile("s_waitcnt vmcnt(0)" ::: "memory");
        __syncthreads();
        cur ^= 1;
    }

    float inv = 1.0f / rs;
    #pragma unroll
    for (int mb = 0; mb < 4; ++mb)
        #pragma unroll
        for (int r = 0; r < 4; ++r)
            ctxb[(size_t)(q0 + ln) * D_MODEL + h * 64 + mb * 16 + g * 4 + r] =
                f2bf(acc[mb][r] * inv);
}

// ---------------- host side ----------------
extern "C" void kernel_launch(void* const* d_in, const int* in_sizes, int n_in,
                              void* d_out, int out_size, void* d_ws, size_t ws_size,
                              hipStream_t stream) {
    const float* x  = (const float*)d_in[0];
    const float* Wq = (const float*)d_in[1];
    const float* Wk = (const float*)d_in[2];
    const float* Wv = (const float*)d_in[3];
    const float* Wo = (const float*)d_in[4];
    const int* tpos = (const int*)d_in[5];
    float* out = (float*)d_out;

    char* ws = (char*)d_ws;
    unsigned short* xb   = (unsigned short*)(ws + 0);            // 8 MB
    unsigned short* Wqb  = (unsigned short*)(ws + (8u << 20));   // 2 MB
    unsigned short* Wkb  = (unsigned short*)(ws + (10u << 20));  // 2 MB
    unsigned short* Wvb  = (unsigned short*)(ws + (12u << 20));  // 2 MB
    unsigned short* Wob  = (unsigned short*)(ws + (14u << 20));  // 2 MB
    unsigned short* Qbuf = (unsigned short*)(ws + (16u << 20));  // 8 MB
    unsigned short* Kbuf = (unsigned short*)(ws + (24u << 20));  // 8 MB
    unsigned short* Vtb  = (unsigned short*)(ws + (32u << 20));  // 8 MB
    unsigned short* ctxb = (unsigned short*)(ws + (40u << 20));  // 8 MB
    unsigned short* Vrow = ctxb;  // alias: Vrow dead before attn writes ctxb
    float* costab = (float*)(ws + (48u << 20));                  // 512 KB
    float* sintab = (float*)(ws + (48u << 20) + (512u << 10));   // 512 KB

    to_bf16_k<<<4096, 256, 0, stream>>>(x, xb, S_LEN * D_MODEL);
    to_bf16_k<<<1024, 256, 0, stream>>>(Wq, Wqb, D_MODEL * D_MODEL);
    to_bf16_k<<<1024, 256, 0, stream>>>(Wk, Wkb, D_MODEL * D_MODEL);
    to_bf16_k<<<1024, 256, 0, stream>>>(Wv, Wvb, D_MODEL * D_MODEL);
    to_bf16_k<<<1024, 256, 0, stream>>>(Wo, Wob, D_MODEL * D_MODEL);
    rope_tables_k<<<512, 256, 0, stream>>>(tpos, costab, sintab);

    dim3 gg(D_MODEL / 128, S_LEN / 128);   // (8, 32)
    // Q: RoPE + pre-scale by scale*log2e (attn uses exp2 domain)
    gemm_nt_k<1><<<gg, 256, 0, stream>>>(xb, Wqb, Qbuf, S_LEN, D_MODEL, D_MODEL,
                                         costab, sintab, SCALE_LOG2E);
    // K: RoPE only
    gemm_nt_k<1><<<gg, 256, 0, stream>>>(xb, Wkb, Kbuf, S_LEN, D_MODEL, D_MODEL,
                                         costab, sintab, 1.0f);
    // V: plain bf16, row-major (transposed next)
    gemm_nt_k<0><<<gg, 256, 0, stream>>>(xb, Wvb, Vrow, S_LEN, D_MODEL, D_MODEL,
                                         nullptr, nullptr, 1.0f);
    // V transpose: Vrow [S][1024] -> Vt [1024][S]
    vtrans_k<<<dim3(S_LEN / 64, D_MODEL / 64), 256, 0, stream>>>(Vrow, Vtb);

    attn_k<<<dim3(N_HEADS, S_LEN / 64), 256, 0, stream>>>(Qbuf, Kbuf, Vtb, ctxb);

    gemm_nt_k<2><<<gg, 256, 0, stream>>>(ctxb, Wob, out, S_LEN, D_MODEL, D_MODEL,
                                         nullptr, nullptr, 1.0f);
}